// Round 11
// baseline (487.776 us; speedup 1.0000x reference)
//
#include <hip/hip_runtime.h>
#include <hip/hip_bf16.h>

// Problem constants (MultiHeadAttention: B=4, S=2048, D=1024, H=16, Dk=64)
#define B_SZ 4
#define S_SZ 2048
#define D_SZ 1024
#define H_SZ 16
#define DK_SZ 64
#define M_ROWS (B_SZ * S_SZ)   // 8192

typedef __bf16 bf16x8 __attribute__((ext_vector_type(8)));
typedef __bf16 bf16x4 __attribute__((ext_vector_type(4)));
typedef float  f32x4  __attribute__((ext_vector_type(4)));

typedef __attribute__((address_space(3))) unsigned int lds_u32;
typedef const __attribute__((address_space(1))) unsigned int glob_u32;

// load 8 contiguous elements -> bf16x8 (fp32 source converts during staging)
__device__ __forceinline__ bf16x8 load8(const float* p) {
    f32x4 a = *(const f32x4*)p;
    f32x4 b = *(const f32x4*)(p + 4);
    bf16x8 r;
    r[0] = (__bf16)a[0]; r[1] = (__bf16)a[1]; r[2] = (__bf16)a[2]; r[3] = (__bf16)a[3];
    r[4] = (__bf16)b[0]; r[5] = (__bf16)b[1]; r[6] = (__bf16)b[2]; r[7] = (__bf16)b[3];
    return r;
}
__device__ __forceinline__ bf16x8 load8(const __bf16* p) {
    return *(const bf16x8*)p;
}

// ---------------------------------------------------------------------------
// fp32 -> bf16 elementwise convert (vectorized, grid-stride). n8 = n/8.
// ---------------------------------------------------------------------------
__global__ __launch_bounds__(256)
void conv_bf16(const float* __restrict__ in, __bf16* __restrict__ out, int n8) {
    int i = blockIdx.x * 256 + threadIdx.x;
    const int stride = gridDim.x * 256;
    for (; i < n8; i += stride)
        *(bf16x8*)&out[(size_t)i * 8] = load8(in + (size_t)i * 8);
}

// ---------------------------------------------------------------------------
// bf16 MFMA GEMM NT + bias, 2-phase pipelined (verified rounds 9-10).
// XCD swizzle (grid 64x8); XOR-granule swizzle both-sides.
// ---------------------------------------------------------------------------
template <typename TC>
__global__ __launch_bounds__(256, 2)
void gemm_nt_bias_g(const __bf16* __restrict__ A, const __bf16* __restrict__ W,
                    const float* __restrict__ bias, TC* __restrict__ C,
                    int M, int N, int K) {
    __shared__ __align__(16) __bf16 sA[2][128 * 64];   // 2 x 16 KiB
    __shared__ __align__(16) __bf16 sB[2][128 * 64];   // 2 x 16 KiB
    const int tid = threadIdx.x;
    const int w = tid >> 6, lane = tid & 63;

    int mt, nt;
    if (gridDim.x == 64 && gridDim.y == 8) {           // XCD-aware remap
        const int lin = blockIdx.x + blockIdx.y * 64;  // dispatch order
        const int xcd = lin & 7, idx = lin >> 3;       // 64 blocks per XCD
        mt = xcd * 8 + (idx >> 3);                     // 8 M-panels per XCD
        nt = idx & 7;                                  // n fastest within XCD
    } else { mt = blockIdx.x; nt = blockIdx.y; }
    const int m0 = mt * 128, n0 = nt * 128;

    const int wr = w >> 1, wc = w & 1;
    const int lr = lane & 15, lq = lane >> 4;

    // staging: issue i covers segment seg=i*4+w (8 rows); lane -> 16B granule
    const int st_roff = lane >> 3;                 // row&7 of staged row
    const int st_cg   = (lane & 7) ^ st_roff;      // pre-swizzled global granule

    f32x4 acc[4][4] = {};

    auto STAGE = [&](int kt, int bsel) {
#pragma unroll
        for (int i = 0; i < 4; ++i) {
            const int seg = i * 4 + w;
            const int row = seg * 8 + st_roff;
            __builtin_amdgcn_global_load_lds(
                (glob_u32*)(A + (size_t)(m0 + row) * K + kt + st_cg * 8),
                (lds_u32*)(&sA[bsel][seg * 512]), 16, 0, 0);
            __builtin_amdgcn_global_load_lds(
                (glob_u32*)(W + (size_t)(n0 + row) * K + kt + st_cg * 8),
                (lds_u32*)(&sB[bsel][seg * 512]), 16, 0, 0);
        }
    };
    auto COMPUTE = [&](int bsel) {
#pragma unroll
        for (int s = 0; s < 2; ++s) {
            bf16x8 av[4], bv[4];
#pragma unroll
            for (int i = 0; i < 4; ++i)
                av[i] = *(const bf16x8*)&sA[bsel][(wr * 64 + i * 16 + lr) * 64
                                                  + (((s * 4 + lq) ^ (lr & 7)) << 3)];
#pragma unroll
            for (int j = 0; j < 4; ++j)
                bv[j] = *(const bf16x8*)&sB[bsel][(wc * 64 + j * 16 + lr) * 64
                                                  + (((s * 4 + lq) ^ (lr & 7)) << 3)];
#pragma unroll
            for (int i = 0; i < 4; ++i)
#pragma unroll
                for (int j = 0; j < 4; ++j)
                    acc[i][j] = __builtin_amdgcn_mfma_f32_16x16x32_bf16(
                        av[i], bv[j], acc[i][j], 0, 0, 0);
        }
    };

    STAGE(0, 0);
    __syncthreads();                 // drain prologue staging
    int buf = 0;
    for (int kt = 64; kt < K; kt += 64) {
        STAGE(kt, buf ^ 1);          // issue next tile first (loads in flight)
        COMPUTE(buf);                // MFMA hides load latency
        __syncthreads();             // one vmcnt-drain barrier per K-step
        buf ^= 1;
    }
    COMPUTE(buf);                    // last tile, no barrier needed

    // epilogue: C/D layout row=lq*4+r, col=lr
#pragma unroll
    for (int j = 0; j < 4; ++j) {
        const int col = n0 + wc * 64 + j * 16 + lr;
        const float bias_f = bias[col];
#pragma unroll
        for (int i = 0; i < 4; ++i) {
            const int rbase = m0 + wr * 64 + i * 16 + lq * 4;
#pragma unroll
            for (int r = 0; r < 4; ++r)
                C[(size_t)(rbase + r) * N + col] = (TC)(acc[i][j][r] + bias_f);
        }
    }
}

// ---------------------------------------------------------------------------
// MFMA GEMM NT + bias, reg-staged (verified; FALLBACK path only).
// ---------------------------------------------------------------------------
#define SAST 72
template <typename TA, typename TW, typename TC>
__global__ __launch_bounds__(256, 2)
void gemm_nt_bias(const TA* __restrict__ A, const TW* __restrict__ W,
                  const float* __restrict__ bias, TC* __restrict__ C,
                  int M, int N, int K) {
    __shared__ __align__(16) __bf16 sA[128 * SAST];
    __shared__ __align__(16) __bf16 sB[128 * SAST];
    const int tid = threadIdx.x;
    const int w = tid >> 6, lane = tid & 63;
    const int m0 = blockIdx.x * 128, n0 = blockIdx.y * 128;
    const int wr = w >> 1, wc = w & 1;
    const int lr = lane & 15, lq = lane >> 4;

    f32x4 acc[4][4] = {};

    for (int kt = 0; kt < K; kt += 64) {
        for (int it = 0; it < 4; ++it) {
            const int c = it * 256 + tid;
            const int row = c >> 3, col8 = c & 7;
            *(bf16x8*)&sA[row * SAST + col8 * 8] =
                load8(A + (size_t)(m0 + row) * K + kt + col8 * 8);
            *(bf16x8*)&sB[row * SAST + col8 * 8] =
                load8(W + (size_t)(n0 + row) * K + kt + col8 * 8);
        }
        __syncthreads();
        for (int s = 0; s < 2; ++s) {
            bf16x8 av[4], bv[4];
            for (int i = 0; i < 4; ++i)
                av[i] = *(const bf16x8*)&sA[(wr * 64 + i * 16 + lr) * SAST + s * 32 + lq * 8];
            for (int j = 0; j < 4; ++j)
                bv[j] = *(const bf16x8*)&sB[(wc * 64 + j * 16 + lr) * SAST + s * 32 + lq * 8];
            for (int i = 0; i < 4; ++i)
                for (int j = 0; j < 4; ++j)
                    acc[i][j] = __builtin_amdgcn_mfma_f32_16x16x32_bf16(
                        av[i], bv[j], acc[i][j], 0, 0, 0);
        }
        __syncthreads();
    }
    for (int j = 0; j < 4; ++j) {
        const int col = n0 + wc * 64 + j * 16 + lr;
        const float bias_f = bias[col];
        for (int i = 0; i < 4; ++i) {
            const int rbase = m0 + wr * 64 + i * 16 + lq * 4;
            for (int r = 0; r < 4; ++r)
                C[(size_t)(rbase + r) * N + col] = (TC)(acc[i][j][r] + bias_f);
        }
    }
}

// ---------------------------------------------------------------------------
// Flash attention v4: round-10 pipeline + 4 blocks/CU occupancy.
// LDS cut 50 -> 40 KiB (163840/40960 = 4.0 exactly; 1024 blocks co-resident,
// single round, no tail):
//   sP 18 -> 8 KiB: per-wave slot reused QSET-SEQUENTIALLY (store P(qs), read
//   pf(qs) immediately; same-wave DS ordering — rounds-4-6-verified idiom),
//   PST=72 pad replaced by the sK XOR-granule swizzle (stride 128B would be
//   16-way conflicted unpadded; XOR spreads granules like sK/sVt).
// Everything else identical to round-10 v3 (1 barrier/tile, K gload_lds dbuf,
// T14 V issue-early/write-late, XCD swizzle, defer-max, swapped QK^T).
// ---------------------------------------------------------------------------
#define KVB 64
__global__ __launch_bounds__(256, 4)
void attn_kernel(const __bf16* qm, const __bf16* __restrict__ km,
                 const __bf16* __restrict__ vm, __bf16* ctx) {
    __shared__ __align__(16) __bf16 sK[2][KVB * 64];    // 16 KiB
    __shared__ __align__(16) __bf16 sVt[2][64 * KVB];   // 16 KiB
    __shared__ __align__(16) __bf16 sP[4][16 * 64];     // 8 KiB (per-wave, reused per qset)

    const int tid = threadIdx.x, w = tid >> 6, lane = tid & 63;
    const int lr = lane & 15, lq = lane >> 4;

    int qblk, bh;
    if (gridDim.x == 16 && gridDim.y == 64) {          // XCD-aware remap
        const int lin = blockIdx.x + blockIdx.y * 16;
        const int xcd = lin & 7, idx = lin >> 3;       // 128 blocks per XCD
        bh = xcd * 8 + (idx >> 4);                     // 8 bh per XCD
        qblk = idx & 15;
    } else { qblk = blockIdx.x; bh = blockIdx.y; }
    const int b = bh >> 4, h = bh & 15;
    const int q0 = qblk * 128;
    const size_t rowbase = (size_t)b * S_SZ;
    const int hoff = h * DK_SZ;

    // Q fragments, B-operand layout: lane&15 = q row, lane>>4 = k-chunk.
    bf16x8 qf[2][2];
#pragma unroll
    for (int qs = 0; qs < 2; ++qs) {
        const __bf16* qp = qm + (rowbase + q0 + w * 32 + qs * 16 + lr) * D_SZ + hoff;
        qf[qs][0] = *(const bf16x8*)(qp + lq * 8);
        qf[qs][1] = *(const bf16x8*)(qp + 32 + lq * 8);
    }

    float mrow[2] = {-1e30f, -1e30f};
    float lrow[2] = {0.f, 0.f};
    f32x4 o[2][4] = {};

    // K staging: wave w, issue i covers keys w*16+i*8..+7; lane -> 16B granule.
    const int gl_koff = (lane >> 3);
    const int gl_c8 = lane & 7;
    // V staging: pass p -> key = p*32 + (tid>>3), d-granule = tid&7.
    const int v_key7 = tid >> 3, v_d8 = tid & 7;
    const int cb0 = (((v_key7 >> 3) ^ v_d8) << 3) + (v_key7 & 7);          // key = v_key7
    const int cb1 = ((((32 + v_key7) >> 3) ^ v_d8) << 3) + (v_key7 & 7);   // key = 32+v_key7

    // sP addressing (XOR-granule swizzled, stride 64 elems = 128 B):
    //   store (b64): logical granule nt*2+(lq>>1), half (lq&1)
    //   read  (b128): logical granule s*4+lq
    const int sp_row = lr * 64;
    const int sp_xor = lr & 7;

    const __bf16* kbase = km + rowbase * D_SZ + hoff;
    const __bf16* vbase = vm + rowbase * D_SZ + hoff;

    auto stageK = [&](int k0t, int bsel) {
#pragma unroll
        for (int i = 0; i < 2; ++i) {
            const int key = w * 16 + i * 8 + gl_koff;   // key&7 == gl_koff
            const __bf16* gp = kbase + (size_t)(k0t + key) * D_SZ
                               + ((gl_c8 ^ gl_koff) << 3);
            __builtin_amdgcn_global_load_lds(
                (glob_u32*)gp, (lds_u32*)(&sK[bsel][(w * 2 + i) * 512]), 16, 0, 0);
        }
    };

    // ---- prologue: stage tile 0 into buffer 0
    stageK(0, 0);
    {
        bf16x8 a0 = *(const bf16x8*)(vbase + (size_t)(v_key7) * D_SZ + (v_d8 << 3));
        bf16x8 a1 = *(const bf16x8*)(vbase + (size_t)(32 + v_key7) * D_SZ + (v_d8 << 3));
#pragma unroll
        for (int e = 0; e < 8; ++e) {
            sVt[0][(v_d8 * 8 + e) * 64 + cb0] = a0[e];
            sVt[0][(v_d8 * 8 + e) * 64 + cb1] = a1[e];
        }
    }
    __syncthreads();

    int buf = 0;
    for (int k0 = 0; k0 < S_SZ; k0 += KVB) {
        const bool more = (k0 + KVB) < S_SZ;
        bf16x8 nv0, nv1;
        if (more) {   // issue next tile's loads early (hide under compute)
            stageK(k0 + KVB, buf ^ 1);
            nv0 = *(const bf16x8*)(vbase + (size_t)(k0 + KVB + v_key7) * D_SZ + (v_d8 << 3));
            nv1 = *(const bf16x8*)(vbase + (size_t)(k0 + KVB + 32 + v_key7) * D_SZ + (v_d8 << 3));
        }

        // ---- QK^T (swapped): sc[qs][nt][r] = dot(K[key], Q[q]),
        //      key = nt*16 + lq*4 + r, q = (wave,qs) + lr.
        f32x4 sc[2][4] = {};
#pragma unroll
        for (int s = 0; s < 2; ++s) {
            bf16x8 kf[4];
#pragma unroll
            for (int nt = 0; nt < 4; ++nt)
                kf[nt] = *(const bf16x8*)&sK[buf][(nt * 16 + lr) * 64
                                                  + (((s * 4 + lq) ^ (lr & 7)) << 3)];
#pragma unroll
            for (int nt = 0; nt < 4; ++nt) {
                sc[0][nt] = __builtin_amdgcn_mfma_f32_16x16x32_bf16(
                    kf[nt], qf[0][s], sc[0][nt], 0, 0, 0);
                sc[1][nt] = __builtin_amdgcn_mfma_f32_16x16x32_bf16(
                    kf[nt], qf[1][s], sc[1][nt], 0, 0, 0);
            }
        }

        // ---- online softmax per qset (scale = 1/sqrt(64) = 0.125);
        //      P round-trips through the per-wave sP slot (reused per qset).
        bf16x8 pf[2][2];
#pragma unroll
        for (int qs = 0; qs < 2; ++qs) {
            float sv[4][4];
            float mt = -1e30f;
#pragma unroll
            for (int nt = 0; nt < 4; ++nt)
#pragma unroll
                for (int r = 0; r < 4; ++r) {
                    sv[nt][r] = sc[qs][nt][r] * 0.125f;
                    mt = fmaxf(mt, sv[nt][r]);
                }
            mt = fmaxf(mt, __shfl_xor(mt, 16));
            mt = fmaxf(mt, __shfl_xor(mt, 32));
            // defer-max: only rescale when some row grew past threshold
            if (!__all(mt - mrow[qs] <= 8.f)) {
                const float mn = fmaxf(mrow[qs], mt);
                const float al = __expf(mrow[qs] - mn);
                mrow[qs] = mn;
                lrow[qs] *= al;
                float a4[4];
#pragma unroll
                for (int r = 0; r < 4; ++r)
                    a4[r] = __shfl(al, ((lane >> 4) << 2) + r, 64);
#pragma unroll
                for (int nt = 0; nt < 4; ++nt)
#pragma unroll
                    for (int r = 0; r < 4; ++r)
                        o[qs][nt][r] *= a4[r];
            }
            float ls = 0.f;
#pragma unroll
            for (int nt = 0; nt < 4; ++nt) {
                bf16x4 pk;
#pragma unroll
                for (int r = 0; r < 4; ++r) {
                    const float pv = __expf(sv[nt][r] - mrow[qs]);
                    ls += pv;
                    pk[r] = (__bf16)pv;
                }
                // store P[q=lr][key = nt*16 + lq*4 + r], swizzled b64
                *(bf16x4*)&sP[w][sp_row
                                 + (((nt * 2 + (lq >> 1)) ^ sp_xor) << 3)
                                 + ((lq & 1) << 2)] = pk;
            }
            ls += __shfl_xor(ls, 16);
            ls += __shfl_xor(ls, 32);
            lrow[qs] += ls;

            // read back this qset's A-fragments (same-wave DS ordering)
#pragma unroll
            for (int s = 0; s < 2; ++s)
                pf[qs][s] = *(const bf16x8*)&sP[w][sp_row
                                                   + (((s * 4 + lq) ^ sp_xor) << 3)];
        }

        // ---- PV
#pragma unroll
        for (int s = 0; s < 2; ++s)
#pragma unroll
            for (int nt = 0; nt < 4; ++nt) {
                bf16x8 vf = *(const bf16x8*)&sVt[buf][
                    (nt * 16 + lr) * 64
                    + (((s * 4 + lq) ^ (nt * 2 + (lr >> 3))) << 3)];
                o[0][nt] = __builtin_amdgcn_mfma_f32_16x16x32_bf16(
                    pf[0][s], vf, o[0][nt], 0, 0, 0);
                o[1][nt] = __builtin_amdgcn_mfma_f32_16x16x32_bf16(
                    pf[1][s], vf, o[1][nt], 0, 0, 0);
            }

        if (more) {   // late write of next V tile (other buffer), then barrier
#pragma unroll
            for (int e = 0; e < 8; ++e) {
                sVt[buf ^ 1][(v_d8 * 8 + e) * 64 + cb0] = nv0[e];
                sVt[buf ^ 1][(v_d8 * 8 + e) * 64 + cb1] = nv1[e];
            }
            __syncthreads();
        }
        buf ^= 1;
    }

    // ---- epilogue: divide by l (broadcast lane&15 -> row lq*4+r), write ctx
#pragma unroll
    for (int qs = 0; qs < 2; ++qs) {
        const float linv = 1.f / lrow[qs];
        float l4[4];
#pragma unroll
        for (int r = 0; r < 4; ++r)
            l4[r] = __shfl(linv, ((lane >> 4) << 2) + r, 64);
#pragma unroll
        for (int nt = 0; nt < 4; ++nt) {
            const int col = hoff + nt * 16 + lr;
#pragma unroll
            for (int r = 0; r < 4; ++r) {
                const size_t row = rowbase + q0 + w * 32 + qs * 16 + lq * 4 + r;
                ctx[row * D_SZ + col] = (__bf16)(o[qs][nt][r] * l4[r]);
            }
        }
    }
}

// ---------------------------------------------------------------------------
extern "C" void kernel_launch(void* const* d_in, const int* in_sizes, int n_in,
                              void* d_out, int out_size, void* d_ws, size_t ws_size,
                              hipStream_t stream) {
    const float* Q  = (const float*)d_in[0];
    const float* K  = (const float*)d_in[1];
    const float* V  = (const float*)d_in[2];
    const float* Wq = (const float*)d_in[3];
    const float* bq = (const float*)d_in[4];
    const float* Wk = (const float*)d_in[5];
    const float* bk = (const float*)d_in[6];
    const float* Wv = (const float*)d_in[7];
    const float* bv = (const float*)d_in[8];
    const float* Wo = (const float*)d_in[9];
    const float* bo = (const float*)d_in[10];
    float* out = (float*)d_out;

    const size_t plane = (size_t)M_ROWS * D_SZ;   // 8.4M elems
    const size_t wsz   = (size_t)D_SZ * D_SZ;     // 1M elems
    const dim3 gg(M_ROWS / 128, D_SZ / 128), bb(256);
    const dim3 ag(S_SZ / 128, B_SZ * H_SZ);

    // Fast path: pre-convert Q/K/V and weights to bf16, then all-bf16 GEMMs
    // with pipelined global_load_lds staging.
    const size_t need_fast = (3 * plane + 4 * wsz) * sizeof(__bf16);
    if (ws_size >= need_fast) {
        __bf16* s0  = (__bf16*)d_ws;            // Qb / Kb / Vb (sequential reuse)
        __bf16* qw  = s0 + plane;               // q-proj out, later ctx (in-place)
        __bf16* kw  = s0 + 2 * plane;           // k-proj out
        __bf16* wgt = s0 + 3 * plane;           // Wqb,Wkb,Wvb,Wob
        __bf16* vw  = (__bf16*)d_out;           // v-proj out in d_out scratch
        const int p8 = (int)(plane / 8), w8 = (int)(wsz / 8);

        conv_bf16<<<512, bb, 0, stream>>>(Wq, wgt, w8);
        conv_bf16<<<512, bb, 0, stream>>>(Wk, wgt + wsz, w8);
        conv_bf16<<<512, bb, 0, stream>>>(Wv, wgt + 2 * wsz, w8);
        conv_bf16<<<512, bb, 0, stream>>>(Wo, wgt + 3 * wsz, w8);

        conv_bf16<<<2048, bb, 0, stream>>>(Q, s0, p8);
        gemm_nt_bias_g<__bf16><<<gg, bb, 0, stream>>>(
            s0, wgt, bq, qw, M_ROWS, D_SZ, D_SZ);
        conv_bf16<<<2048, bb, 0, stream>>>(K, s0, p8);
        gemm_nt_bias_g<__bf16><<<gg, bb, 0, stream>>>(
            s0, wgt + wsz, bk, kw, M_ROWS, D_SZ, D_SZ);
        conv_bf16<<<2048, bb, 0, stream>>>(V, s0, p8);
        gemm_nt_bias_g<__bf16><<<gg, bb, 0, stream>>>(
            s0, wgt + 2 * wsz, bv, vw, M_ROWS, D_SZ, D_SZ);

        attn_kernel<<<ag, bb, 0, stream>>>(qw, kw, vw, qw);

        gemm_nt_bias_g<float><<<gg, bb, 0, stream>>>(
            qw, wgt + 3 * wsz, bo, out, M_ROWS, D_SZ, D_SZ);
        return;
    }

    // Fallback (verified round-4 path): fp32 reg-staged GEMMs, 2 bf16 planes.
    if (ws_size < 2 * plane * sizeof(__bf16)) return;
    __bf16* qw = (__bf16*)d_ws;
    __bf16* kw = qw + plane;
    __bf16* vw = (__bf16*)d_out;
    __bf16* cw = qw;

    gemm_nt_bias<float, float, __bf16><<<gg, bb, 0, stream>>>(Q, Wq, bq, qw, M_ROWS, D_SZ, D_SZ);
    gemm_nt_bias<float, float, __bf16><<<gg, bb, 0, stream>>>(K, Wk, bk, kw, M_ROWS, D_SZ, D_SZ);
    gemm_nt_bias<float, float, __bf16><<<gg, bb, 0, stream>>>(V, Wv, bv, vw, M_ROWS, D_SZ, D_SZ);

    attn_kernel<<<ag, bb, 0, stream>>>(qw, kw, vw, cw);

    gemm_nt_bias<__bf16, float, float><<<gg, bb, 0, stream>>>(cw, Wo, bo, out,
                                                              M_ROWS, D_SZ, D_SZ);
}

// Round 12
// 395.088 us; speedup vs baseline: 1.2346x; 1.2346x over previous
//
#include <hip/hip_runtime.h>
#include <hip/hip_bf16.h>

// Problem constants (MultiHeadAttention: B=4, S=2048, D=1024, H=16, Dk=64)
#define B_SZ 4
#define S_SZ 2048
#define D_SZ 1024
#define H_SZ 16
#define DK_SZ 64
#define M_ROWS (B_SZ * S_SZ)   // 8192

typedef __bf16 bf16x8 __attribute__((ext_vector_type(8)));
typedef __bf16 bf16x4 __attribute__((ext_vector_type(4)));
typedef float  f32x4  __attribute__((ext_vector_type(4)));

typedef __attribute__((address_space(3))) unsigned int lds_u32;
typedef const __attribute__((address_space(1))) unsigned int glob_u32;

// load 8 contiguous elements -> bf16x8 (fp32 source converts during staging)
__device__ __forceinline__ bf16x8 load8(const float* p) {
    f32x4 a = *(const f32x4*)p;
    f32x4 b = *(const f32x4*)(p + 4);
    bf16x8 r;
    r[0] = (__bf16)a[0]; r[1] = (__bf16)a[1]; r[2] = (__bf16)a[2]; r[3] = (__bf16)a[3];
    r[4] = (__bf16)b[0]; r[5] = (__bf16)b[1]; r[6] = (__bf16)b[2]; r[7] = (__bf16)b[3];
    return r;
}
__device__ __forceinline__ bf16x8 load8(const __bf16* p) {
    return *(const bf16x8*)p;
}

// ---------------------------------------------------------------------------
// fp32 -> bf16 elementwise convert (vectorized, grid-stride). n8 = n/8.
// ---------------------------------------------------------------------------
__global__ __launch_bounds__(256)
void conv_bf16(const float* __restrict__ in, __bf16* __restrict__ out, int n8) {
    int i = blockIdx.x * 256 + threadIdx.x;
    const int stride = gridDim.x * 256;
    for (; i < n8; i += stride)
        *(bf16x8*)&out[(size_t)i * 8] = load8(in + (size_t)i * 8);
}

// ---------------------------------------------------------------------------
// bf16 MFMA GEMM NT + bias, 2-phase pipelined (verified rounds 9-10).
// XCD swizzle (grid 64x8); XOR-granule swizzle both-sides.
// ---------------------------------------------------------------------------
template <typename TC>
__global__ __launch_bounds__(256, 2)
void gemm_nt_bias_g(const __bf16* __restrict__ A, const __bf16* __restrict__ W,
                    const float* __restrict__ bias, TC* __restrict__ C,
                    int M, int N, int K) {
    __shared__ __align__(16) __bf16 sA[2][128 * 64];   // 2 x 16 KiB
    __shared__ __align__(16) __bf16 sB[2][128 * 64];   // 2 x 16 KiB
    const int tid = threadIdx.x;
    const int w = tid >> 6, lane = tid & 63;

    int mt, nt;
    if (gridDim.x == 64 && gridDim.y == 8) {           // XCD-aware remap
        const int lin = blockIdx.x + blockIdx.y * 64;  // dispatch order
        const int xcd = lin & 7, idx = lin >> 3;       // 64 blocks per XCD
        mt = xcd * 8 + (idx >> 3);                     // 8 M-panels per XCD
        nt = idx & 7;                                  // n fastest within XCD
    } else { mt = blockIdx.x; nt = blockIdx.y; }
    const int m0 = mt * 128, n0 = nt * 128;

    const int wr = w >> 1, wc = w & 1;
    const int lr = lane & 15, lq = lane >> 4;

    // staging: issue i covers segment seg=i*4+w (8 rows); lane -> 16B granule
    const int st_roff = lane >> 3;                 // row&7 of staged row
    const int st_cg   = (lane & 7) ^ st_roff;      // pre-swizzled global granule

    f32x4 acc[4][4] = {};

    auto STAGE = [&](int kt, int bsel) {
#pragma unroll
        for (int i = 0; i < 4; ++i) {
            const int seg = i * 4 + w;
            const int row = seg * 8 + st_roff;
            __builtin_amdgcn_global_load_lds(
                (glob_u32*)(A + (size_t)(m0 + row) * K + kt + st_cg * 8),
                (lds_u32*)(&sA[bsel][seg * 512]), 16, 0, 0);
            __builtin_amdgcn_global_load_lds(
                (glob_u32*)(W + (size_t)(n0 + row) * K + kt + st_cg * 8),
                (lds_u32*)(&sB[bsel][seg * 512]), 16, 0, 0);
        }
    };
    auto COMPUTE = [&](int bsel) {
#pragma unroll
        for (int s = 0; s < 2; ++s) {
            bf16x8 av[4], bv[4];
#pragma unroll
            for (int i = 0; i < 4; ++i)
                av[i] = *(const bf16x8*)&sA[bsel][(wr * 64 + i * 16 + lr) * 64
                                                  + (((s * 4 + lq) ^ (lr & 7)) << 3)];
#pragma unroll
            for (int j = 0; j < 4; ++j)
                bv[j] = *(const bf16x8*)&sB[bsel][(wc * 64 + j * 16 + lr) * 64
                                                  + (((s * 4 + lq) ^ (lr & 7)) << 3)];
#pragma unroll
            for (int i = 0; i < 4; ++i)
#pragma unroll
                for (int j = 0; j < 4; ++j)
                    acc[i][j] = __builtin_amdgcn_mfma_f32_16x16x32_bf16(
                        av[i], bv[j], acc[i][j], 0, 0, 0);
        }
    };

    STAGE(0, 0);
    __syncthreads();                 // drain prologue staging
    int buf = 0;
    for (int kt = 64; kt < K; kt += 64) {
        STAGE(kt, buf ^ 1);          // issue next tile first (loads in flight)
        COMPUTE(buf);                // MFMA hides load latency
        __syncthreads();             // one vmcnt-drain barrier per K-step
        buf ^= 1;
    }
    COMPUTE(buf);                    // last tile, no barrier needed

    // epilogue: C/D layout row=lq*4+r, col=lr
#pragma unroll
    for (int j = 0; j < 4; ++j) {
        const int col = n0 + wc * 64 + j * 16 + lr;
        const float bias_f = bias[col];
#pragma unroll
        for (int i = 0; i < 4; ++i) {
            const int rbase = m0 + wr * 64 + i * 16 + lq * 4;
#pragma unroll
            for (int r = 0; r < 4; ++r)
                C[(size_t)(rbase + r) * N + col] = (TC)(acc[i][j][r] + bias_f);
        }
    }
}

// ---------------------------------------------------------------------------
// MFMA GEMM NT + bias, reg-staged (verified; FALLBACK path only).
// ---------------------------------------------------------------------------
#define SAST 72
template <typename TA, typename TW, typename TC>
__global__ __launch_bounds__(256, 2)
void gemm_nt_bias(const TA* __restrict__ A, const TW* __restrict__ W,
                  const float* __restrict__ bias, TC* __restrict__ C,
                  int M, int N, int K) {
    __shared__ __align__(16) __bf16 sA[128 * SAST];
    __shared__ __align__(16) __bf16 sB[128 * SAST];
    const int tid = threadIdx.x;
    const int w = tid >> 6, lane = tid & 63;
    const int m0 = blockIdx.x * 128, n0 = blockIdx.y * 128;
    const int wr = w >> 1, wc = w & 1;
    const int lr = lane & 15, lq = lane >> 4;

    f32x4 acc[4][4] = {};

    for (int kt = 0; kt < K; kt += 64) {
        for (int it = 0; it < 4; ++it) {
            const int c = it * 256 + tid;
            const int row = c >> 3, col8 = c & 7;
            *(bf16x8*)&sA[row * SAST + col8 * 8] =
                load8(A + (size_t)(m0 + row) * K + kt + col8 * 8);
            *(bf16x8*)&sB[row * SAST + col8 * 8] =
                load8(W + (size_t)(n0 + row) * K + kt + col8 * 8);
        }
        __syncthreads();
        for (int s = 0; s < 2; ++s) {
            bf16x8 av[4], bv[4];
            for (int i = 0; i < 4; ++i)
                av[i] = *(const bf16x8*)&sA[(wr * 64 + i * 16 + lr) * SAST + s * 32 + lq * 8];
            for (int j = 0; j < 4; ++j)
                bv[j] = *(const bf16x8*)&sB[(wc * 64 + j * 16 + lr) * SAST + s * 32 + lq * 8];
            for (int i = 0; i < 4; ++i)
                for (int j = 0; j < 4; ++j)
                    acc[i][j] = __builtin_amdgcn_mfma_f32_16x16x32_bf16(
                        av[i], bv[j], acc[i][j], 0, 0, 0);
        }
        __syncthreads();
    }
    for (int j = 0; j < 4; ++j) {
        const int col = n0 + wc * 64 + j * 16 + lr;
        const float bias_f = bias[col];
        for (int i = 0; i < 4; ++i) {
            const int rbase = m0 + wr * 64 + i * 16 + lq * 4;
            for (int r = 0; r < 4; ++r)
                C[(size_t)(rbase + r) * N + col] = (TC)(acc[i][j][r] + bias_f);
        }
    }
}

// ---------------------------------------------------------------------------
// Flash attention v4.1: round-11 structure, spill-free occupancy.
// Round-11 post-mortem: __launch_bounds__(256,4) capped the UNIFIED VGPR+AGPR
// file at 128/wave; live state ~140 -> spill (VGPR 64, WRITE_SIZE 172 MB,
// dur 227us). Fix: (256,3) -> cap 170, no spill; LDS 40 KiB still allows 4
// but registers set residency at 3 blocks/CU (+50% waves vs round 10).
// Everything else identical to round 11 (correctness-verified, absmax same).
// ---------------------------------------------------------------------------
#define KVB 64
__global__ __launch_bounds__(256, 3)
void attn_kernel(const __bf16* qm, const __bf16* __restrict__ km,
                 const __bf16* __restrict__ vm, __bf16* ctx) {
    __shared__ __align__(16) __bf16 sK[2][KVB * 64];    // 16 KiB
    __shared__ __align__(16) __bf16 sVt[2][64 * KVB];   // 16 KiB
    __shared__ __align__(16) __bf16 sP[4][16 * 64];     // 8 KiB (per-wave, reused per qset)

    const int tid = threadIdx.x, w = tid >> 6, lane = tid & 63;
    const int lr = lane & 15, lq = lane >> 4;

    int qblk, bh;
    if (gridDim.x == 16 && gridDim.y == 64) {          // XCD-aware remap
        const int lin = blockIdx.x + blockIdx.y * 16;
        const int xcd = lin & 7, idx = lin >> 3;       // 128 blocks per XCD
        bh = xcd * 8 + (idx >> 4);                     // 8 bh per XCD
        qblk = idx & 15;
    } else { qblk = blockIdx.x; bh = blockIdx.y; }
    const int b = bh >> 4, h = bh & 15;
    const int q0 = qblk * 128;
    const size_t rowbase = (size_t)b * S_SZ;
    const int hoff = h * DK_SZ;

    // Q fragments, B-operand layout: lane&15 = q row, lane>>4 = k-chunk.
    bf16x8 qf[2][2];
#pragma unroll
    for (int qs = 0; qs < 2; ++qs) {
        const __bf16* qp = qm + (rowbase + q0 + w * 32 + qs * 16 + lr) * D_SZ + hoff;
        qf[qs][0] = *(const bf16x8*)(qp + lq * 8);
        qf[qs][1] = *(const bf16x8*)(qp + 32 + lq * 8);
    }

    float mrow[2] = {-1e30f, -1e30f};
    float lrow[2] = {0.f, 0.f};
    f32x4 o[2][4] = {};

    // K staging: wave w, issue i covers keys w*16+i*8..+7; lane -> 16B granule.
    const int gl_koff = (lane >> 3);
    const int gl_c8 = lane & 7;
    // V staging: pass p -> key = p*32 + (tid>>3), d-granule = tid&7.
    const int v_key7 = tid >> 3, v_d8 = tid & 7;
    const int cb0 = (((v_key7 >> 3) ^ v_d8) << 3) + (v_key7 & 7);          // key = v_key7
    const int cb1 = ((((32 + v_key7) >> 3) ^ v_d8) << 3) + (v_key7 & 7);   // key = 32+v_key7

    // sP addressing (XOR-granule swizzled, stride 64 elems = 128 B):
    //   store (b64): logical granule nt*2+(lq>>1), half (lq&1)
    //   read  (b128): logical granule s*4+lq
    const int sp_row = lr * 64;
    const int sp_xor = lr & 7;

    const __bf16* kbase = km + rowbase * D_SZ + hoff;
    const __bf16* vbase = vm + rowbase * D_SZ + hoff;

    auto stageK = [&](int k0t, int bsel) {
#pragma unroll
        for (int i = 0; i < 2; ++i) {
            const int key = w * 16 + i * 8 + gl_koff;   // key&7 == gl_koff
            const __bf16* gp = kbase + (size_t)(k0t + key) * D_SZ
                               + ((gl_c8 ^ gl_koff) << 3);
            __builtin_amdgcn_global_load_lds(
                (glob_u32*)gp, (lds_u32*)(&sK[bsel][(w * 2 + i) * 512]), 16, 0, 0);
        }
    };

    // ---- prologue: stage tile 0 into buffer 0
    stageK(0, 0);
    {
        bf16x8 a0 = *(const bf16x8*)(vbase + (size_t)(v_key7) * D_SZ + (v_d8 << 3));
        bf16x8 a1 = *(const bf16x8*)(vbase + (size_t)(32 + v_key7) * D_SZ + (v_d8 << 3));
#pragma unroll
        for (int e = 0; e < 8; ++e) {
            sVt[0][(v_d8 * 8 + e) * 64 + cb0] = a0[e];
            sVt[0][(v_d8 * 8 + e) * 64 + cb1] = a1[e];
        }
    }
    __syncthreads();

    int buf = 0;
    for (int k0 = 0; k0 < S_SZ; k0 += KVB) {
        const bool more = (k0 + KVB) < S_SZ;
        bf16x8 nv0, nv1;
        if (more) {   // issue next tile's loads early (hide under compute)
            stageK(k0 + KVB, buf ^ 1);
            nv0 = *(const bf16x8*)(vbase + (size_t)(k0 + KVB + v_key7) * D_SZ + (v_d8 << 3));
            nv1 = *(const bf16x8*)(vbase + (size_t)(k0 + KVB + 32 + v_key7) * D_SZ + (v_d8 << 3));
        }

        // ---- QK^T (swapped): sc[qs][nt][r] = dot(K[key], Q[q]),
        //      key = nt*16 + lq*4 + r, q = (wave,qs) + lr.
        f32x4 sc[2][4] = {};
#pragma unroll
        for (int s = 0; s < 2; ++s) {
            bf16x8 kf[4];
#pragma unroll
            for (int nt = 0; nt < 4; ++nt)
                kf[nt] = *(const bf16x8*)&sK[buf][(nt * 16 + lr) * 64
                                                  + (((s * 4 + lq) ^ (lr & 7)) << 3)];
#pragma unroll
            for (int nt = 0; nt < 4; ++nt) {
                sc[0][nt] = __builtin_amdgcn_mfma_f32_16x16x32_bf16(
                    kf[nt], qf[0][s], sc[0][nt], 0, 0, 0);
                sc[1][nt] = __builtin_amdgcn_mfma_f32_16x16x32_bf16(
                    kf[nt], qf[1][s], sc[1][nt], 0, 0, 0);
            }
        }

        // ---- online softmax per qset (scale = 1/sqrt(64) = 0.125);
        //      P round-trips through the per-wave sP slot (reused per qset).
        bf16x8 pf[2][2];
#pragma unroll
        for (int qs = 0; qs < 2; ++qs) {
            float sv[4][4];
            float mt = -1e30f;
#pragma unroll
            for (int nt = 0; nt < 4; ++nt)
#pragma unroll
                for (int r = 0; r < 4; ++r) {
                    sv[nt][r] = sc[qs][nt][r] * 0.125f;
                    mt = fmaxf(mt, sv[nt][r]);
                }
            mt = fmaxf(mt, __shfl_xor(mt, 16));
            mt = fmaxf(mt, __shfl_xor(mt, 32));
            // defer-max: only rescale when some row grew past threshold
            if (!__all(mt - mrow[qs] <= 8.f)) {
                const float mn = fmaxf(mrow[qs], mt);
                const float al = __expf(mrow[qs] - mn);
                mrow[qs] = mn;
                lrow[qs] *= al;
                float a4[4];
#pragma unroll
                for (int r = 0; r < 4; ++r)
                    a4[r] = __shfl(al, ((lane >> 4) << 2) + r, 64);
#pragma unroll
                for (int nt = 0; nt < 4; ++nt)
#pragma unroll
                    for (int r = 0; r < 4; ++r)
                        o[qs][nt][r] *= a4[r];
            }
            float ls = 0.f;
#pragma unroll
            for (int nt = 0; nt < 4; ++nt) {
                bf16x4 pk;
#pragma unroll
                for (int r = 0; r < 4; ++r) {
                    const float pv = __expf(sv[nt][r] - mrow[qs]);
                    ls += pv;
                    pk[r] = (__bf16)pv;
                }
                // store P[q=lr][key = nt*16 + lq*4 + r], swizzled b64
                *(bf16x4*)&sP[w][sp_row
                                 + (((nt * 2 + (lq >> 1)) ^ sp_xor) << 3)
                                 + ((lq & 1) << 2)] = pk;
            }
            ls += __shfl_xor(ls, 16);
            ls += __shfl_xor(ls, 32);
            lrow[qs] += ls;

            // read back this qset's A-fragments (same-wave DS ordering)
#pragma unroll
            for (int s = 0; s < 2; ++s)
                pf[qs][s] = *(const bf16x8*)&sP[w][sp_row
                                                   + (((s * 4 + lq) ^ sp_xor) << 3)];
        }

        // ---- PV
#pragma unroll
        for (int s = 0; s < 2; ++s)
#pragma unroll
            for (int nt = 0; nt < 4; ++nt) {
                bf16x8 vf = *(const bf16x8*)&sVt[buf][
                    (nt * 16 + lr) * 64
                    + (((s * 4 + lq) ^ (nt * 2 + (lr >> 3))) << 3)];
                o[0][nt] = __builtin_amdgcn_mfma_f32_16x16x32_bf16(
                    pf[0][s], vf, o[0][nt], 0, 0, 0);
                o[1][nt] = __builtin_amdgcn_mfma_f32_16x16x32_bf16(
                    pf[1][s], vf, o[1][nt], 0, 0, 0);
            }

        if (more) {   // late write of next V tile (other buffer), then barrier
#pragma unroll
            for (int e = 0; e < 8; ++e) {
                sVt[buf ^ 1][(v_d8 * 8 + e) * 64 + cb0] = nv0[e];
                sVt[buf ^ 1][(v_d8 * 8 + e) * 64 + cb1] = nv1[e];
            }
            __syncthreads();
        }
        buf ^= 1;
    }

    // ---- epilogue: divide by l (broadcast lane&15 -> row lq*4+r), write ctx
#pragma unroll
    for (int qs = 0; qs < 2; ++qs) {
        const float linv = 1.f / lrow[qs];
        float l4[4];
#pragma unroll
        for (int r = 0; r < 4; ++r)
            l4[r] = __shfl(linv, ((lane >> 4) << 2) + r, 64);
#pragma unroll
        for (int nt = 0; nt < 4; ++nt) {
            const int col = hoff + nt * 16 + lr;
#pragma unroll
            for (int r = 0; r < 4; ++r) {
                const size_t row = rowbase + q0 + w * 32 + qs * 16 + lq * 4 + r;
                ctx[row * D_SZ + col] = (__bf16)(o[qs][nt][r] * l4[r]);
            }
        }
    }
}

// ---------------------------------------------------------------------------
extern "C" void kernel_launch(void* const* d_in, const int* in_sizes, int n_in,
                              void* d_out, int out_size, void* d_ws, size_t ws_size,
                              hipStream_t stream) {
    const float* Q  = (const float*)d_in[0];
    const float* K  = (const float*)d_in[1];
    const float* V  = (const float*)d_in[2];
    const float* Wq = (const float*)d_in[3];
    const float* bq = (const float*)d_in[4];
    const float* Wk = (const float*)d_in[5];
    const float* bk = (const float*)d_in[6];
    const float* Wv = (const float*)d_in[7];
    const float* bv = (const float*)d_in[8];
    const float* Wo = (const float*)d_in[9];
    const float* bo = (const float*)d_in[10];
    float* out = (float*)d_out;

    const size_t plane = (size_t)M_ROWS * D_SZ;   // 8.4M elems
    const size_t wsz   = (size_t)D_SZ * D_SZ;     // 1M elems
    const dim3 gg(M_ROWS / 128, D_SZ / 128), bb(256);
    const dim3 ag(S_SZ / 128, B_SZ * H_SZ);

    // Fast path: pre-convert Q/K/V and weights to bf16, then all-bf16 GEMMs
    // with pipelined global_load_lds staging.
    const size_t need_fast = (3 * plane + 4 * wsz) * sizeof(__bf16);
    if (ws_size >= need_fast) {
        __bf16* s0  = (__bf16*)d_ws;            // Qb / Kb / Vb (sequential reuse)
        __bf16* qw  = s0 + plane;               // q-proj out, later ctx (in-place)
        __bf16* kw  = s0 + 2 * plane;           // k-proj out
        __bf16* wgt = s0 + 3 * plane;           // Wqb,Wkb,Wvb,Wob
        __bf16* vw  = (__bf16*)d_out;           // v-proj out in d_out scratch
        const int p8 = (int)(plane / 8), w8 = (int)(wsz / 8);

        conv_bf16<<<512, bb, 0, stream>>>(Wq, wgt, w8);
        conv_bf16<<<512, bb, 0, stream>>>(Wk, wgt + wsz, w8);
        conv_bf16<<<512, bb, 0, stream>>>(Wv, wgt + 2 * wsz, w8);
        conv_bf16<<<512, bb, 0, stream>>>(Wo, wgt + 3 * wsz, w8);

        conv_bf16<<<2048, bb, 0, stream>>>(Q, s0, p8);
        gemm_nt_bias_g<__bf16><<<gg, bb, 0, stream>>>(
            s0, wgt, bq, qw, M_ROWS, D_SZ, D_SZ);
        conv_bf16<<<2048, bb, 0, stream>>>(K, s0, p8);
        gemm_nt_bias_g<__bf16><<<gg, bb, 0, stream>>>(
            s0, wgt + wsz, bk, kw, M_ROWS, D_SZ, D_SZ);
        conv_bf16<<<2048, bb, 0, stream>>>(V, s0, p8);
        gemm_nt_bias_g<__bf16><<<gg, bb, 0, stream>>>(
            s0, wgt + 2 * wsz, bv, vw, M_ROWS, D_SZ, D_SZ);

        attn_kernel<<<ag, bb, 0, stream>>>(qw, kw, vw, qw);

        gemm_nt_bias_g<float><<<gg, bb, 0, stream>>>(
            qw, wgt + 3 * wsz, bo, out, M_ROWS, D_SZ, D_SZ);
        return;
    }

    // Fallback (verified round-4 path): fp32 reg-staged GEMMs, 2 bf16 planes.
    if (ws_size < 2 * plane * sizeof(__bf16)) return;
    __bf16* qw = (__bf16*)d_ws;
    __bf16* kw = qw + plane;
    __bf16* vw = (__bf16*)d_out;
    __bf16* cw = qw;

    gemm_nt_bias<float, float, __bf16><<<gg, bb, 0, stream>>>(Q, Wq, bq, qw, M_ROWS, D_SZ, D_SZ);
    gemm_nt_bias<float, float, __bf16><<<gg, bb, 0, stream>>>(K, Wk, bk, kw, M_ROWS, D_SZ, D_SZ);
    gemm_nt_bias<float, float, __bf16><<<gg, bb, 0, stream>>>(V, Wv, bv, vw, M_ROWS, D_SZ, D_SZ);

    attn_kernel<<<ag, bb, 0, stream>>>(qw, kw, vw, cw);

    gemm_nt_bias<__bf16, float, float><<<gg, bb, 0, stream>>>(cw, Wo, bo, out,
                                                              M_ROWS, D_SZ, D_SZ);
}

// Round 13
// 384.336 us; speedup vs baseline: 1.2691x; 1.0280x over previous
//
#include <hip/hip_runtime.h>
#include <hip/hip_bf16.h>

// Problem constants (MultiHeadAttention: B=4, S=2048, D=1024, H=16, Dk=64)
#define B_SZ 4
#define S_SZ 2048
#define D_SZ 1024
#define H_SZ 16
#define DK_SZ 64
#define M_ROWS (B_SZ * S_SZ)   // 8192

typedef __bf16 bf16x8 __attribute__((ext_vector_type(8)));
typedef __bf16 bf16x4 __attribute__((ext_vector_type(4)));
typedef float  f32x4  __attribute__((ext_vector_type(4)));

typedef __attribute__((address_space(3))) unsigned int lds_u32;
typedef const __attribute__((address_space(1))) unsigned int glob_u32;

// load 8 contiguous elements -> bf16x8 (fp32 source converts during staging)
__device__ __forceinline__ bf16x8 load8(const float* p) {
    f32x4 a = *(const f32x4*)p;
    f32x4 b = *(const f32x4*)(p + 4);
    bf16x8 r;
    r[0] = (__bf16)a[0]; r[1] = (__bf16)a[1]; r[2] = (__bf16)a[2]; r[3] = (__bf16)a[3];
    r[4] = (__bf16)b[0]; r[5] = (__bf16)b[1]; r[6] = (__bf16)b[2]; r[7] = (__bf16)b[3];
    return r;
}
__device__ __forceinline__ bf16x8 load8(const __bf16* p) {
    return *(const bf16x8*)p;
}

// ---------------------------------------------------------------------------
// fp32 -> bf16 elementwise convert (vectorized, grid-stride). n8 = n/8.
// ---------------------------------------------------------------------------
__global__ __launch_bounds__(256)
void conv_bf16(const float* __restrict__ in, __bf16* __restrict__ out, int n8) {
    int i = blockIdx.x * 256 + threadIdx.x;
    const int stride = gridDim.x * 256;
    for (; i < n8; i += stride)
        *(bf16x8*)&out[(size_t)i * 8] = load8(in + (size_t)i * 8);
}

// ---------------------------------------------------------------------------
// bf16 MFMA GEMM NT + bias, 2-phase pipelined (verified rounds 9-12).
// XCD swizzle (grid 64x8); XOR-granule swizzle both-sides.
// ---------------------------------------------------------------------------
template <typename TC>
__global__ __launch_bounds__(256, 2)
void gemm_nt_bias_g(const __bf16* __restrict__ A, const __bf16* __restrict__ W,
                    const float* __restrict__ bias, TC* __restrict__ C,
                    int M, int N, int K) {
    __shared__ __align__(16) __bf16 sA[2][128 * 64];   // 2 x 16 KiB
    __shared__ __align__(16) __bf16 sB[2][128 * 64];   // 2 x 16 KiB
    const int tid = threadIdx.x;
    const int w = tid >> 6, lane = tid & 63;

    int mt, nt;
    if (gridDim.x == 64 && gridDim.y == 8) {           // XCD-aware remap
        const int lin = blockIdx.x + blockIdx.y * 64;  // dispatch order
        const int xcd = lin & 7, idx = lin >> 3;       // 64 blocks per XCD
        mt = xcd * 8 + (idx >> 3);                     // 8 M-panels per XCD
        nt = idx & 7;                                  // n fastest within XCD
    } else { mt = blockIdx.x; nt = blockIdx.y; }
    const int m0 = mt * 128, n0 = nt * 128;

    const int wr = w >> 1, wc = w & 1;
    const int lr = lane & 15, lq = lane >> 4;

    // staging: issue i covers segment seg=i*4+w (8 rows); lane -> 16B granule
    const int st_roff = lane >> 3;                 // row&7 of staged row
    const int st_cg   = (lane & 7) ^ st_roff;      // pre-swizzled global granule

    f32x4 acc[4][4] = {};

    auto STAGE = [&](int kt, int bsel) {
#pragma unroll
        for (int i = 0; i < 4; ++i) {
            const int seg = i * 4 + w;
            const int row = seg * 8 + st_roff;
            __builtin_amdgcn_global_load_lds(
                (glob_u32*)(A + (size_t)(m0 + row) * K + kt + st_cg * 8),
                (lds_u32*)(&sA[bsel][seg * 512]), 16, 0, 0);
            __builtin_amdgcn_global_load_lds(
                (glob_u32*)(W + (size_t)(n0 + row) * K + kt + st_cg * 8),
                (lds_u32*)(&sB[bsel][seg * 512]), 16, 0, 0);
        }
    };
    auto COMPUTE = [&](int bsel) {
#pragma unroll
        for (int s = 0; s < 2; ++s) {
            bf16x8 av[4], bv[4];
#pragma unroll
            for (int i = 0; i < 4; ++i)
                av[i] = *(const bf16x8*)&sA[bsel][(wr * 64 + i * 16 + lr) * 64
                                                  + (((s * 4 + lq) ^ (lr & 7)) << 3)];
#pragma unroll
            for (int j = 0; j < 4; ++j)
                bv[j] = *(const bf16x8*)&sB[bsel][(wc * 64 + j * 16 + lr) * 64
                                                  + (((s * 4 + lq) ^ (lr & 7)) << 3)];
#pragma unroll
            for (int i = 0; i < 4; ++i)
#pragma unroll
                for (int j = 0; j < 4; ++j)
                    acc[i][j] = __builtin_amdgcn_mfma_f32_16x16x32_bf16(
                        av[i], bv[j], acc[i][j], 0, 0, 0);
        }
    };

    STAGE(0, 0);
    __syncthreads();                 // drain prologue staging
    int buf = 0;
    for (int kt = 64; kt < K; kt += 64) {
        STAGE(kt, buf ^ 1);          // issue next tile first (loads in flight)
        COMPUTE(buf);                // MFMA hides load latency
        __syncthreads();             // one vmcnt-drain barrier per K-step
        buf ^= 1;
    }
    COMPUTE(buf);                    // last tile, no barrier needed

    // epilogue: C/D layout row=lq*4+r, col=lr
#pragma unroll
    for (int j = 0; j < 4; ++j) {
        const int col = n0 + wc * 64 + j * 16 + lr;
        const float bias_f = bias[col];
#pragma unroll
        for (int i = 0; i < 4; ++i) {
            const int rbase = m0 + wr * 64 + i * 16 + lq * 4;
#pragma unroll
            for (int r = 0; r < 4; ++r)
                C[(size_t)(rbase + r) * N + col] = (TC)(acc[i][j][r] + bias_f);
        }
    }
}

// ---------------------------------------------------------------------------
// MFMA GEMM NT + bias, reg-staged (verified; FALLBACK path only).
// ---------------------------------------------------------------------------
#define SAST 72
template <typename TA, typename TW, typename TC>
__global__ __launch_bounds__(256, 2)
void gemm_nt_bias(const TA* __restrict__ A, const TW* __restrict__ W,
                  const float* __restrict__ bias, TC* __restrict__ C,
                  int M, int N, int K) {
    __shared__ __align__(16) __bf16 sA[128 * SAST];
    __shared__ __align__(16) __bf16 sB[128 * SAST];
    const int tid = threadIdx.x;
    const int w = tid >> 6, lane = tid & 63;
    const int m0 = blockIdx.x * 128, n0 = blockIdx.y * 128;
    const int wr = w >> 1, wc = w & 1;
    const int lr = lane & 15, lq = lane >> 4;

    f32x4 acc[4][4] = {};

    for (int kt = 0; kt < K; kt += 64) {
        for (int it = 0; it < 4; ++it) {
            const int c = it * 256 + tid;
            const int row = c >> 3, col8 = c & 7;
            *(bf16x8*)&sA[row * SAST + col8 * 8] =
                load8(A + (size_t)(m0 + row) * K + kt + col8 * 8);
            *(bf16x8*)&sB[row * SAST + col8 * 8] =
                load8(W + (size_t)(n0 + row) * K + kt + col8 * 8);
        }
        __syncthreads();
        for (int s = 0; s < 2; ++s) {
            bf16x8 av[4], bv[4];
            for (int i = 0; i < 4; ++i)
                av[i] = *(const bf16x8*)&sA[(wr * 64 + i * 16 + lr) * SAST + s * 32 + lq * 8];
            for (int j = 0; j < 4; ++j)
                bv[j] = *(const bf16x8*)&sB[(wc * 64 + j * 16 + lr) * SAST + s * 32 + lq * 8];
            for (int i = 0; i < 4; ++i)
                for (int j = 0; j < 4; ++j)
                    acc[i][j] = __builtin_amdgcn_mfma_f32_16x16x32_bf16(
                        av[i], bv[j], acc[i][j], 0, 0, 0);
        }
        __syncthreads();
    }
    for (int j = 0; j < 4; ++j) {
        const int col = n0 + wc * 64 + j * 16 + lr;
        const float bias_f = bias[col];
        for (int i = 0; i < 4; ++i) {
            const int rbase = m0 + wr * 64 + i * 16 + lq * 4;
            for (int r = 0; r < 4; ++r)
                C[(size_t)(rbase + r) * N + col] = (TC)(acc[i][j][r] + bias_f);
        }
    }
}

// ---------------------------------------------------------------------------
// Flash attention v5: qset-SEQUENTIAL QK^T+softmax to cut peak live regs
// below the 128/wave unified cap, enabling __launch_bounds__(256,4):
//   round-12 analysis: 1024 blocks / (3/CU x 256) = 2 dispatch rounds ->
//   wall = 2T regardless (latency-bound, per-block time ~constant). 4/CU
//   puts ALL 1024 blocks in ONE round -> wall ~T. Round 11 proved 4/CU
//   works but spilled (live ~140 > 128). Fix: sc[2][4]->sc[4] per qset
//   (kf loaded twice per tile: +8 ds_read_b128, cheap; we're latency-bound).
// Everything else identical to round 12 (verified): 1 barrier/tile dbuf,
// XOR swizzles, sP qset-reuse, T14 V staging, XCD swizzle, defer-max.
// ---------------------------------------------------------------------------
#define KVB 64
__global__ __launch_bounds__(256, 4)
void attn_kernel(const __bf16* qm, const __bf16* __restrict__ km,
                 const __bf16* __restrict__ vm, __bf16* ctx) {
    __shared__ __align__(16) __bf16 sK[2][KVB * 64];    // 16 KiB
    __shared__ __align__(16) __bf16 sVt[2][64 * KVB];   // 16 KiB
    __shared__ __align__(16) __bf16 sP[4][16 * 64];     // 8 KiB (per-wave, reused per qset)

    const int tid = threadIdx.x, w = tid >> 6, lane = tid & 63;
    const int lr = lane & 15, lq = lane >> 4;

    int qblk, bh;
    if (gridDim.x == 16 && gridDim.y == 64) {          // XCD-aware remap
        const int lin = blockIdx.x + blockIdx.y * 16;
        const int xcd = lin & 7, idx = lin >> 3;       // 128 blocks per XCD
        bh = xcd * 8 + (idx >> 4);                     // 8 bh per XCD
        qblk = idx & 15;
    } else { qblk = blockIdx.x; bh = blockIdx.y; }
    const int b = bh >> 4, h = bh & 15;
    const int q0 = qblk * 128;
    const size_t rowbase = (size_t)b * S_SZ;
    const int hoff = h * DK_SZ;

    // Q fragments, B-operand layout: lane&15 = q row, lane>>4 = k-chunk.
    bf16x8 qf[2][2];
#pragma unroll
    for (int qs = 0; qs < 2; ++qs) {
        const __bf16* qp = qm + (rowbase + q0 + w * 32 + qs * 16 + lr) * D_SZ + hoff;
        qf[qs][0] = *(const bf16x8*)(qp + lq * 8);
        qf[qs][1] = *(const bf16x8*)(qp + 32 + lq * 8);
    }

    float mrow[2] = {-1e30f, -1e30f};
    float lrow[2] = {0.f, 0.f};
    f32x4 o[2][4] = {};

    // K staging: wave w, issue i covers keys w*16+i*8..+7; lane -> 16B granule.
    const int gl_koff = (lane >> 3);
    const int gl_c8 = lane & 7;
    // V staging: pass p -> key = p*32 + (tid>>3), d-granule = tid&7.
    const int v_key7 = tid >> 3, v_d8 = tid & 7;
    const int cb0 = (((v_key7 >> 3) ^ v_d8) << 3) + (v_key7 & 7);          // key = v_key7
    const int cb1 = ((((32 + v_key7) >> 3) ^ v_d8) << 3) + (v_key7 & 7);   // key = 32+v_key7

    // sP addressing (XOR-granule swizzled, stride 64 elems = 128 B):
    //   store (b64): logical granule nt*2+(lq>>1), half (lq&1)
    //   read  (b128): logical granule s*4+lq
    const int sp_row = lr * 64;
    const int sp_xor = lr & 7;

    const __bf16* kbase = km + rowbase * D_SZ + hoff;
    const __bf16* vbase = vm + rowbase * D_SZ + hoff;

    auto stageK = [&](int k0t, int bsel) {
#pragma unroll
        for (int i = 0; i < 2; ++i) {
            const int key = w * 16 + i * 8 + gl_koff;   // key&7 == gl_koff
            const __bf16* gp = kbase + (size_t)(k0t + key) * D_SZ
                               + ((gl_c8 ^ gl_koff) << 3);
            __builtin_amdgcn_global_load_lds(
                (glob_u32*)gp, (lds_u32*)(&sK[bsel][(w * 2 + i) * 512]), 16, 0, 0);
        }
    };

    // ---- prologue: stage tile 0 into buffer 0
    stageK(0, 0);
    {
        bf16x8 a0 = *(const bf16x8*)(vbase + (size_t)(v_key7) * D_SZ + (v_d8 << 3));
        bf16x8 a1 = *(const bf16x8*)(vbase + (size_t)(32 + v_key7) * D_SZ + (v_d8 << 3));
#pragma unroll
        for (int e = 0; e < 8; ++e) {
            sVt[0][(v_d8 * 8 + e) * 64 + cb0] = a0[e];
            sVt[0][(v_d8 * 8 + e) * 64 + cb1] = a1[e];
        }
    }
    __syncthreads();

    int buf = 0;
    for (int k0 = 0; k0 < S_SZ; k0 += KVB) {
        const bool more = (k0 + KVB) < S_SZ;
        bf16x8 nv0, nv1;
        if (more) {   // issue next tile's loads early (hide under compute)
            stageK(k0 + KVB, buf ^ 1);
            nv0 = *(const bf16x8*)(vbase + (size_t)(k0 + KVB + v_key7) * D_SZ + (v_d8 << 3));
            nv1 = *(const bf16x8*)(vbase + (size_t)(k0 + KVB + 32 + v_key7) * D_SZ + (v_d8 << 3));
        }

        // ---- per qset: QK^T then softmax (sequential -> sc[4] live, not [2][4])
        bf16x8 pf[2][2];
#pragma unroll
        for (int qs = 0; qs < 2; ++qs) {
            f32x4 sc[4] = {};
#pragma unroll
            for (int s = 0; s < 2; ++s) {
                bf16x8 kf[4];
#pragma unroll
                for (int nt = 0; nt < 4; ++nt)
                    kf[nt] = *(const bf16x8*)&sK[buf][(nt * 16 + lr) * 64
                                                      + (((s * 4 + lq) ^ (lr & 7)) << 3)];
#pragma unroll
                for (int nt = 0; nt < 4; ++nt)
                    sc[nt] = __builtin_amdgcn_mfma_f32_16x16x32_bf16(
                        kf[nt], qf[qs][s], sc[nt], 0, 0, 0);
            }

            // softmax (scale = 1/sqrt(64) = 0.125)
            float sv[4][4];
            float mt = -1e30f;
#pragma unroll
            for (int nt = 0; nt < 4; ++nt)
#pragma unroll
                for (int r = 0; r < 4; ++r) {
                    sv[nt][r] = sc[nt][r] * 0.125f;
                    mt = fmaxf(mt, sv[nt][r]);
                }
            mt = fmaxf(mt, __shfl_xor(mt, 16));
            mt = fmaxf(mt, __shfl_xor(mt, 32));
            // defer-max: only rescale when some row grew past threshold
            if (!__all(mt - mrow[qs] <= 8.f)) {
                const float mn = fmaxf(mrow[qs], mt);
                const float al = __expf(mrow[qs] - mn);
                mrow[qs] = mn;
                lrow[qs] *= al;
                float a4[4];
#pragma unroll
                for (int r = 0; r < 4; ++r)
                    a4[r] = __shfl(al, ((lane >> 4) << 2) + r, 64);
#pragma unroll
                for (int nt = 0; nt < 4; ++nt)
#pragma unroll
                    for (int r = 0; r < 4; ++r)
                        o[qs][nt][r] *= a4[r];
            }
            float ls = 0.f;
#pragma unroll
            for (int nt = 0; nt < 4; ++nt) {
                bf16x4 pk;
#pragma unroll
                for (int r = 0; r < 4; ++r) {
                    const float pv = __expf(sv[nt][r] - mrow[qs]);
                    ls += pv;
                    pk[r] = (__bf16)pv;
                }
                // store P[q=lr][key = nt*16 + lq*4 + r], swizzled b64
                *(bf16x4*)&sP[w][sp_row
                                 + (((nt * 2 + (lq >> 1)) ^ sp_xor) << 3)
                                 + ((lq & 1) << 2)] = pk;
            }
            ls += __shfl_xor(ls, 16);
            ls += __shfl_xor(ls, 32);
            lrow[qs] += ls;

            // read back this qset's A-fragments (same-wave DS ordering)
#pragma unroll
            for (int s = 0; s < 2; ++s)
                pf[qs][s] = *(const bf16x8*)&sP[w][sp_row
                                                   + (((s * 4 + lq) ^ sp_xor) << 3)];
        }

        // ---- PV (shared vf feeds both qsets)
#pragma unroll
        for (int s = 0; s < 2; ++s)
#pragma unroll
            for (int nt = 0; nt < 4; ++nt) {
                bf16x8 vf = *(const bf16x8*)&sVt[buf][
                    (nt * 16 + lr) * 64
                    + (((s * 4 + lq) ^ (nt * 2 + (lr >> 3))) << 3)];
                o[0][nt] = __builtin_amdgcn_mfma_f32_16x16x32_bf16(
                    pf[0][s], vf, o[0][nt], 0, 0, 0);
                o[1][nt] = __builtin_amdgcn_mfma_f32_16x16x32_bf16(
                    pf[1][s], vf, o[1][nt], 0, 0, 0);
            }

        if (more) {   // late write of next V tile (other buffer), then barrier
#pragma unroll
            for (int e = 0; e < 8; ++e) {
                sVt[buf ^ 1][(v_d8 * 8 + e) * 64 + cb0] = nv0[e];
                sVt[buf ^ 1][(v_d8 * 8 + e) * 64 + cb1] = nv1[e];
            }
            __syncthreads();
        }
        buf ^= 1;
    }

    // ---- epilogue: divide by l (broadcast lane&15 -> row lq*4+r), write ctx
#pragma unroll
    for (int qs = 0; qs < 2; ++qs) {
        const float linv = 1.f / lrow[qs];
        float l4[4];
#pragma unroll
        for (int r = 0; r < 4; ++r)
            l4[r] = __shfl(linv, ((lane >> 4) << 2) + r, 64);
#pragma unroll
        for (int nt = 0; nt < 4; ++nt) {
            const int col = hoff + nt * 16 + lr;
#pragma unroll
            for (int r = 0; r < 4; ++r) {
                const size_t row = rowbase + q0 + w * 32 + qs * 16 + lq * 4 + r;
                ctx[row * D_SZ + col] = (__bf16)(o[qs][nt][r] * l4[r]);
            }
        }
    }
}

// ---------------------------------------------------------------------------
extern "C" void kernel_launch(void* const* d_in, const int* in_sizes, int n_in,
                              void* d_out, int out_size, void* d_ws, size_t ws_size,
                              hipStream_t stream) {
    const float* Q  = (const float*)d_in[0];
    const float* K  = (const float*)d_in[1];
    const float* V  = (const float*)d_in[2];
    const float* Wq = (const float*)d_in[3];
    const float* bq = (const float*)d_in[4];
    const float* Wk = (const float*)d_in[5];
    const float* bk = (const float*)d_in[6];
    const float* Wv = (const float*)d_in[7];
    const float* bv = (const float*)d_in[8];
    const float* Wo = (const float*)d_in[9];
    const float* bo = (const float*)d_in[10];
    float* out = (float*)d_out;

    const size_t plane = (size_t)M_ROWS * D_SZ;   // 8.4M elems
    const size_t wsz   = (size_t)D_SZ * D_SZ;     // 1M elems
    const dim3 gg(M_ROWS / 128, D_SZ / 128), bb(256);
    const dim3 ag(S_SZ / 128, B_SZ * H_SZ);

    // Fast path: pre-convert Q/K/V and weights to bf16, then all-bf16 GEMMs
    // with pipelined global_load_lds staging.
    const size_t need_fast = (3 * plane + 4 * wsz) * sizeof(__bf16);
    if (ws_size >= need_fast) {
        __bf16* s0  = (__bf16*)d_ws;            // Qb / Kb / Vb (sequential reuse)
        __bf16* qw  = s0 + plane;               // q-proj out, later ctx (in-place)
        __bf16* kw  = s0 + 2 * plane;           // k-proj out
        __bf16* wgt = s0 + 3 * plane;           // Wqb,Wkb,Wvb,Wob
        __bf16* vw  = (__bf16*)d_out;           // v-proj out in d_out scratch
        const int p8 = (int)(plane / 8), w8 = (int)(wsz / 8);

        conv_bf16<<<512, bb, 0, stream>>>(Wq, wgt, w8);
        conv_bf16<<<512, bb, 0, stream>>>(Wk, wgt + wsz, w8);
        conv_bf16<<<512, bb, 0, stream>>>(Wv, wgt + 2 * wsz, w8);
        conv_bf16<<<512, bb, 0, stream>>>(Wo, wgt + 3 * wsz, w8);

        conv_bf16<<<2048, bb, 0, stream>>>(Q, s0, p8);
        gemm_nt_bias_g<__bf16><<<gg, bb, 0, stream>>>(
            s0, wgt, bq, qw, M_ROWS, D_SZ, D_SZ);
        conv_bf16<<<2048, bb, 0, stream>>>(K, s0, p8);
        gemm_nt_bias_g<__bf16><<<gg, bb, 0, stream>>>(
            s0, wgt + wsz, bk, kw, M_ROWS, D_SZ, D_SZ);
        conv_bf16<<<2048, bb, 0, stream>>>(V, s0, p8);
        gemm_nt_bias_g<__bf16><<<gg, bb, 0, stream>>>(
            s0, wgt + 2 * wsz, bv, vw, M_ROWS, D_SZ, D_SZ);

        attn_kernel<<<ag, bb, 0, stream>>>(qw, kw, vw, qw);

        gemm_nt_bias_g<float><<<gg, bb, 0, stream>>>(
            qw, wgt + 3 * wsz, bo, out, M_ROWS, D_SZ, D_SZ);
        return;
    }

    // Fallback (verified round-4 path): fp32 reg-staged GEMMs, 2 bf16 planes.
    if (ws_size < 2 * plane * sizeof(__bf16)) return;
    __bf16* qw = (__bf16*)d_ws;
    __bf16* kw = qw + plane;
    __bf16* vw = (__bf16*)d_out;
    __bf16* cw = qw;

    gemm_nt_bias<float, float, __bf16><<<gg, bb, 0, stream>>>(Q, Wq, bq, qw, M_ROWS, D_SZ, D_SZ);
    gemm_nt_bias<float, float, __bf16><<<gg, bb, 0, stream>>>(K, Wk, bk, kw, M_ROWS, D_SZ, D_SZ);
    gemm_nt_bias<float, float, __bf16><<<gg, bb, 0, stream>>>(V, Wv, bv, vw, M_ROWS, D_SZ, D_SZ);

    attn_kernel<<<ag, bb, 0, stream>>>(qw, kw, vw, cw);

    gemm_nt_bias<__bf16, float, float><<<gg, bb, 0, stream>>>(cw, Wo, bo, out,
                                                              M_ROWS, D_SZ, D_SZ);
}

// Round 14
// 381.614 us; speedup vs baseline: 1.2782x; 1.0071x over previous
//
#include <hip/hip_runtime.h>
#include <hip/hip_bf16.h>

// Problem constants (MultiHeadAttention: B=4, S=2048, D=1024, H=16, Dk=64)
#define B_SZ 4
#define S_SZ 2048
#define D_SZ 1024
#define H_SZ 16
#define DK_SZ 64
#define M_ROWS (B_SZ * S_SZ)   // 8192

typedef __bf16 bf16x8 __attribute__((ext_vector_type(8)));
typedef __bf16 bf16x4 __attribute__((ext_vector_type(4)));
typedef float  f32x4  __attribute__((ext_vector_type(4)));

typedef __attribute__((address_space(3))) unsigned int lds_u32;
typedef const __attribute__((address_space(1))) unsigned int glob_u32;

// load 8 contiguous elements -> bf16x8 (fp32 source converts during staging)
__device__ __forceinline__ bf16x8 load8(const float* p) {
    f32x4 a = *(const f32x4*)p;
    f32x4 b = *(const f32x4*)(p + 4);
    bf16x8 r;
    r[0] = (__bf16)a[0]; r[1] = (__bf16)a[1]; r[2] = (__bf16)a[2]; r[3] = (__bf16)a[3];
    r[4] = (__bf16)b[0]; r[5] = (__bf16)b[1]; r[6] = (__bf16)b[2]; r[7] = (__bf16)b[3];
    return r;
}
__device__ __forceinline__ bf16x8 load8(const __bf16* p) {
    return *(const bf16x8*)p;
}

// ---------------------------------------------------------------------------
// fp32 -> bf16 elementwise convert (vectorized, grid-stride). n8 = n/8.
// ---------------------------------------------------------------------------
__global__ __launch_bounds__(256)
void conv_bf16(const float* __restrict__ in, __bf16* __restrict__ out, int n8) {
    int i = blockIdx.x * 256 + threadIdx.x;
    const int stride = gridDim.x * 256;
    for (; i < n8; i += stride)
        *(bf16x8*)&out[(size_t)i * 8] = load8(in + (size_t)i * 8);
}

// ---------------------------------------------------------------------------
// bf16 MFMA GEMM NT + bias, COUNTED-vmcnt pipeline (T4):
//   rounds 9-13 showed the __syncthreads dbuf is neutral — the compiler
//   emits a full vmcnt(0) drain at each barrier (m99/m100). Fix per T4/m218:
//   raw s_barrier + inline-asm s_waitcnt vmcnt(8). Each wave issues exactly
//   8 global_load_lds per K-tile (4 segs x {A,W}); code is wave-symmetric so
//   per-wave vmcnt counting is sound (m201 template):
//     {vmcnt(8); barrier; COMPUTE(buf); barrier; STAGE(t+2 -> buf)}
//   -> tile t+1's DMA stays in flight across BOTH barriers; only the final
//   tile takes a vmcnt(0).
//   Race audit: barrier-1 = all waves waited own vmcnt -> all tile-t loads
//   landed. barrier-2 = all reads of buf done before overwrite issues.
// XCD swizzle (grid 64x8); XOR-granule swizzle both-sides (verified r6-13).
// ---------------------------------------------------------------------------
template <typename TC>
__global__ __launch_bounds__(256, 2)
void gemm_nt_bias_g(const __bf16* __restrict__ A, const __bf16* __restrict__ W,
                    const float* __restrict__ bias, TC* __restrict__ C,
                    int M, int N, int K) {
    __shared__ __align__(16) __bf16 sA[2][128 * 64];   // 2 x 16 KiB
    __shared__ __align__(16) __bf16 sB[2][128 * 64];   // 2 x 16 KiB
    const int tid = threadIdx.x;
    const int w = tid >> 6, lane = tid & 63;

    int mt, nt;
    if (gridDim.x == 64 && gridDim.y == 8) {           // XCD-aware remap
        const int lin = blockIdx.x + blockIdx.y * 64;  // dispatch order
        const int xcd = lin & 7, idx = lin >> 3;       // 64 blocks per XCD
        mt = xcd * 8 + (idx >> 3);                     // 8 M-panels per XCD
        nt = idx & 7;                                  // n fastest within XCD
    } else { mt = blockIdx.x; nt = blockIdx.y; }
    const int m0 = mt * 128, n0 = nt * 128;

    const int wr = w >> 1, wc = w & 1;
    const int lr = lane & 15, lq = lane >> 4;

    // staging: issue i covers segment seg=i*4+w (8 rows); lane -> 16B granule
    const int st_roff = lane >> 3;                 // row&7 of staged row
    const int st_cg   = (lane & 7) ^ st_roff;      // pre-swizzled global granule

    f32x4 acc[4][4] = {};

    auto STAGE = [&](int kt, int bsel) {           // exactly 8 gload_lds/wave
#pragma unroll
        for (int i = 0; i < 4; ++i) {
            const int seg = i * 4 + w;
            const int row = seg * 8 + st_roff;
            __builtin_amdgcn_global_load_lds(
                (glob_u32*)(A + (size_t)(m0 + row) * K + kt + st_cg * 8),
                (lds_u32*)(&sA[bsel][seg * 512]), 16, 0, 0);
            __builtin_amdgcn_global_load_lds(
                (glob_u32*)(W + (size_t)(n0 + row) * K + kt + st_cg * 8),
                (lds_u32*)(&sB[bsel][seg * 512]), 16, 0, 0);
        }
    };
    auto COMPUTE = [&](int bsel) {
#pragma unroll
        for (int s = 0; s < 2; ++s) {
            bf16x8 av[4], bv[4];
#pragma unroll
            for (int i = 0; i < 4; ++i)
                av[i] = *(const bf16x8*)&sA[bsel][(wr * 64 + i * 16 + lr) * 64
                                                  + (((s * 4 + lq) ^ (lr & 7)) << 3)];
#pragma unroll
            for (int j = 0; j < 4; ++j)
                bv[j] = *(const bf16x8*)&sB[bsel][(wc * 64 + j * 16 + lr) * 64
                                                  + (((s * 4 + lq) ^ (lr & 7)) << 3)];
#pragma unroll
            for (int i = 0; i < 4; ++i)
#pragma unroll
                for (int j = 0; j < 4; ++j)
                    acc[i][j] = __builtin_amdgcn_mfma_f32_16x16x32_bf16(
                        av[i], bv[j], acc[i][j], 0, 0, 0);
        }
    };

    STAGE(0, 0);
    STAGE(64, 1);                    // 16 loads in flight
    int buf = 0;
    for (int kt = 0; kt + 64 < K; kt += 64) {      // tiles 0..nt-2
        asm volatile("s_waitcnt vmcnt(8)" ::: "memory");   // this tile landed
        __builtin_amdgcn_s_barrier();              // all waves' tile landed
        COMPUTE(buf);
        __builtin_amdgcn_s_barrier();              // all reads of buf done
        if (kt + 128 < K) STAGE(kt + 128, buf);    // overwrite freed buffer
        buf ^= 1;
    }
    asm volatile("s_waitcnt vmcnt(0)" ::: "memory");       // final tile
    __builtin_amdgcn_s_barrier();
    COMPUTE(buf);

    // epilogue: C/D layout row=lq*4+r, col=lr
#pragma unroll
    for (int j = 0; j < 4; ++j) {
        const int col = n0 + wc * 64 + j * 16 + lr;
        const float bias_f = bias[col];
#pragma unroll
        for (int i = 0; i < 4; ++i) {
            const int rbase = m0 + wr * 64 + i * 16 + lq * 4;
#pragma unroll
            for (int r = 0; r < 4; ++r)
                C[(size_t)(rbase + r) * N + col] = (TC)(acc[i][j][r] + bias_f);
        }
    }
}

// ---------------------------------------------------------------------------
// MFMA GEMM NT + bias, reg-staged (verified; FALLBACK path only).
// ---------------------------------------------------------------------------
#define SAST 72
template <typename TA, typename TW, typename TC>
__global__ __launch_bounds__(256, 2)
void gemm_nt_bias(const TA* __restrict__ A, const TW* __restrict__ W,
                  const float* __restrict__ bias, TC* __restrict__ C,
                  int M, int N, int K) {
    __shared__ __align__(16) __bf16 sA[128 * SAST];
    __shared__ __align__(16) __bf16 sB[128 * SAST];
    const int tid = threadIdx.x;
    const int w = tid >> 6, lane = tid & 63;
    const int m0 = blockIdx.x * 128, n0 = blockIdx.y * 128;
    const int wr = w >> 1, wc = w & 1;
    const int lr = lane & 15, lq = lane >> 4;

    f32x4 acc[4][4] = {};

    for (int kt = 0; kt < K; kt += 64) {
        for (int it = 0; it < 4; ++it) {
            const int c = it * 256 + tid;
            const int row = c >> 3, col8 = c & 7;
            *(bf16x8*)&sA[row * SAST + col8 * 8] =
                load8(A + (size_t)(m0 + row) * K + kt + col8 * 8);
            *(bf16x8*)&sB[row * SAST + col8 * 8] =
                load8(W + (size_t)(n0 + row) * K + kt + col8 * 8);
        }
        __syncthreads();
        for (int s = 0; s < 2; ++s) {
            bf16x8 av[4], bv[4];
            for (int i = 0; i < 4; ++i)
                av[i] = *(const bf16x8*)&sA[(wr * 64 + i * 16 + lr) * SAST + s * 32 + lq * 8];
            for (int j = 0; j < 4; ++j)
                bv[j] = *(const bf16x8*)&sB[(wc * 64 + j * 16 + lr) * SAST + s * 32 + lq * 8];
            for (int i = 0; i < 4; ++i)
                for (int j = 0; j < 4; ++j)
                    acc[i][j] = __builtin_amdgcn_mfma_f32_16x16x32_bf16(
                        av[i], bv[j], acc[i][j], 0, 0, 0);
        }
        __syncthreads();
    }
    for (int j = 0; j < 4; ++j) {
        const int col = n0 + wc * 64 + j * 16 + lr;
        const float bias_f = bias[col];
        for (int i = 0; i < 4; ++i) {
            const int rbase = m0 + wr * 64 + i * 16 + lq * 4;
            for (int r = 0; r < 4; ++r)
                C[(size_t)(rbase + r) * N + col] = (TC)(acc[i][j][r] + bias_f);
        }
    }
}

// ---------------------------------------------------------------------------
// Flash attention v5 (verified round 13: 142 us, Occ 38%). Unchanged.
// qset-sequential QK^T+softmax; 4 blocks/CU; 1-barrier/tile dbuf pipeline;
// XOR swizzles; sP qset-reuse; T14 V staging; XCD swizzle; defer-max.
// ---------------------------------------------------------------------------
#define KVB 64
__global__ __launch_bounds__(256, 4)
void attn_kernel(const __bf16* qm, const __bf16* __restrict__ km,
                 const __bf16* __restrict__ vm, __bf16* ctx) {
    __shared__ __align__(16) __bf16 sK[2][KVB * 64];    // 16 KiB
    __shared__ __align__(16) __bf16 sVt[2][64 * KVB];   // 16 KiB
    __shared__ __align__(16) __bf16 sP[4][16 * 64];     // 8 KiB (per-wave, reused per qset)

    const int tid = threadIdx.x, w = tid >> 6, lane = tid & 63;
    const int lr = lane & 15, lq = lane >> 4;

    int qblk, bh;
    if (gridDim.x == 16 && gridDim.y == 64) {          // XCD-aware remap
        const int lin = blockIdx.x + blockIdx.y * 16;
        const int xcd = lin & 7, idx = lin >> 3;       // 128 blocks per XCD
        bh = xcd * 8 + (idx >> 4);                     // 8 bh per XCD
        qblk = idx & 15;
    } else { qblk = blockIdx.x; bh = blockIdx.y; }
    const int b = bh >> 4, h = bh & 15;
    const int q0 = qblk * 128;
    const size_t rowbase = (size_t)b * S_SZ;
    const int hoff = h * DK_SZ;

    // Q fragments, B-operand layout: lane&15 = q row, lane>>4 = k-chunk.
    bf16x8 qf[2][2];
#pragma unroll
    for (int qs = 0; qs < 2; ++qs) {
        const __bf16* qp = qm + (rowbase + q0 + w * 32 + qs * 16 + lr) * D_SZ + hoff;
        qf[qs][0] = *(const bf16x8*)(qp + lq * 8);
        qf[qs][1] = *(const bf16x8*)(qp + 32 + lq * 8);
    }

    float mrow[2] = {-1e30f, -1e30f};
    float lrow[2] = {0.f, 0.f};
    f32x4 o[2][4] = {};

    // K staging: wave w, issue i covers keys w*16+i*8..+7; lane -> 16B granule.
    const int gl_koff = (lane >> 3);
    const int gl_c8 = lane & 7;
    // V staging: pass p -> key = p*32 + (tid>>3), d-granule = tid&7.
    const int v_key7 = tid >> 3, v_d8 = tid & 7;
    const int cb0 = (((v_key7 >> 3) ^ v_d8) << 3) + (v_key7 & 7);          // key = v_key7
    const int cb1 = ((((32 + v_key7) >> 3) ^ v_d8) << 3) + (v_key7 & 7);   // key = 32+v_key7

    // sP addressing (XOR-granule swizzled, stride 64 elems = 128 B)
    const int sp_row = lr * 64;
    const int sp_xor = lr & 7;

    const __bf16* kbase = km + rowbase * D_SZ + hoff;
    const __bf16* vbase = vm + rowbase * D_SZ + hoff;

    auto stageK = [&](int k0t, int bsel) {
#pragma unroll
        for (int i = 0; i < 2; ++i) {
            const int key = w * 16 + i * 8 + gl_koff;   // key&7 == gl_koff
            const __bf16* gp = kbase + (size_t)(k0t + key) * D_SZ
                               + ((gl_c8 ^ gl_koff) << 3);
            __builtin_amdgcn_global_load_lds(
                (glob_u32*)gp, (lds_u32*)(&sK[bsel][(w * 2 + i) * 512]), 16, 0, 0);
        }
    };

    // ---- prologue: stage tile 0 into buffer 0
    stageK(0, 0);
    {
        bf16x8 a0 = *(const bf16x8*)(vbase + (size_t)(v_key7) * D_SZ + (v_d8 << 3));
        bf16x8 a1 = *(const bf16x8*)(vbase + (size_t)(32 + v_key7) * D_SZ + (v_d8 << 3));
#pragma unroll
        for (int e = 0; e < 8; ++e) {
            sVt[0][(v_d8 * 8 + e) * 64 + cb0] = a0[e];
            sVt[0][(v_d8 * 8 + e) * 64 + cb1] = a1[e];
        }
    }
    __syncthreads();

    int buf = 0;
    for (int k0 = 0; k0 < S_SZ; k0 += KVB) {
        const bool more = (k0 + KVB) < S_SZ;
        bf16x8 nv0, nv1;
        if (more) {   // issue next tile's loads early (hide under compute)
            stageK(k0 + KVB, buf ^ 1);
            nv0 = *(const bf16x8*)(vbase + (size_t)(k0 + KVB + v_key7) * D_SZ + (v_d8 << 3));
            nv1 = *(const bf16x8*)(vbase + (size_t)(k0 + KVB + 32 + v_key7) * D_SZ + (v_d8 << 3));
        }

        // ---- per qset: QK^T then softmax (sequential -> sc[4] live, not [2][4])
        bf16x8 pf[2][2];
#pragma unroll
        for (int qs = 0; qs < 2; ++qs) {
            f32x4 sc[4] = {};
#pragma unroll
            for (int s = 0; s < 2; ++s) {
                bf16x8 kf[4];
#pragma unroll
                for (int nt = 0; nt < 4; ++nt)
                    kf[nt] = *(const bf16x8*)&sK[buf][(nt * 16 + lr) * 64
                                                      + (((s * 4 + lq) ^ (lr & 7)) << 3)];
#pragma unroll
                for (int nt = 0; nt < 4; ++nt)
                    sc[nt] = __builtin_amdgcn_mfma_f32_16x16x32_bf16(
                        kf[nt], qf[qs][s], sc[nt], 0, 0, 0);
            }

            // softmax (scale = 1/sqrt(64) = 0.125)
            float sv[4][4];
            float mt = -1e30f;
#pragma unroll
            for (int nt = 0; nt < 4; ++nt)
#pragma unroll
                for (int r = 0; r < 4; ++r) {
                    sv[nt][r] = sc[nt][r] * 0.125f;
                    mt = fmaxf(mt, sv[nt][r]);
                }
            mt = fmaxf(mt, __shfl_xor(mt, 16));
            mt = fmaxf(mt, __shfl_xor(mt, 32));
            // defer-max: only rescale when some row grew past threshold
            if (!__all(mt - mrow[qs] <= 8.f)) {
                const float mn = fmaxf(mrow[qs], mt);
                const float al = __expf(mrow[qs] - mn);
                mrow[qs] = mn;
                lrow[qs] *= al;
                float a4[4];
#pragma unroll
                for (int r = 0; r < 4; ++r)
                    a4[r] = __shfl(al, ((lane >> 4) << 2) + r, 64);
#pragma unroll
                for (int nt = 0; nt < 4; ++nt)
#pragma unroll
                    for (int r = 0; r < 4; ++r)
                        o[qs][nt][r] *= a4[r];
            }
            float ls = 0.f;
#pragma unroll
            for (int nt = 0; nt < 4; ++nt) {
                bf16x4 pk;
#pragma unroll
                for (int r = 0; r < 4; ++r) {
                    const float pv = __expf(sv[nt][r] - mrow[qs]);
                    ls += pv;
                    pk[r] = (__bf16)pv;
                }
                // store P[q=lr][key = nt*16 + lq*4 + r], swizzled b64
                *(bf16x4*)&sP[w][sp_row
                                 + (((nt * 2 + (lq >> 1)) ^ sp_xor) << 3)
                                 + ((lq & 1) << 2)] = pk;
            }
            ls += __shfl_xor(ls, 16);
            ls += __shfl_xor(ls, 32);
            lrow[qs] += ls;

            // read back this qset's A-fragments (same-wave DS ordering)
#pragma unroll
            for (int s = 0; s < 2; ++s)
                pf[qs][s] = *(const bf16x8*)&sP[w][sp_row
                                                   + (((s * 4 + lq) ^ sp_xor) << 3)];
        }

        // ---- PV (shared vf feeds both qsets)
#pragma unroll
        for (int s = 0; s < 2; ++s)
#pragma unroll
            for (int nt = 0; nt < 4; ++nt) {
                bf16x8 vf = *(const bf16x8*)&sVt[buf][
                    (nt * 16 + lr) * 64
                    + (((s * 4 + lq) ^ (nt * 2 + (lr >> 3))) << 3)];
                o[0][nt] = __builtin_amdgcn_mfma_f32_16x16x32_bf16(
                    pf[0][s], vf, o[0][nt], 0, 0, 0);
                o[1][nt] = __builtin_amdgcn_mfma_f32_16x16x32_bf16(
                    pf[1][s], vf, o[1][nt], 0, 0, 0);
            }

        if (more) {   // late write of next V tile (other buffer), then barrier
#pragma unroll
            for (int e = 0; e < 8; ++e) {
                sVt[buf ^ 1][(v_d8 * 8 + e) * 64 + cb0] = nv0[e];
                sVt[buf ^ 1][(v_d8 * 8 + e) * 64 + cb1] = nv1[e];
            }
            __syncthreads();
        }
        buf ^= 1;
    }

    // ---- epilogue: divide by l (broadcast lane&15 -> row lq*4+r), write ctx
#pragma unroll
    for (int qs = 0; qs < 2; ++qs) {
        const float linv = 1.f / lrow[qs];
        float l4[4];
#pragma unroll
        for (int r = 0; r < 4; ++r)
            l4[r] = __shfl(linv, ((lane >> 4) << 2) + r, 64);
#pragma unroll
        for (int nt = 0; nt < 4; ++nt) {
            const int col = hoff + nt * 16 + lr;
#pragma unroll
            for (int r = 0; r < 4; ++r) {
                const size_t row = rowbase + q0 + w * 32 + qs * 16 + lq * 4 + r;
                ctx[row * D_SZ + col] = (__bf16)(o[qs][nt][r] * l4[r]);
            }
        }
    }
}

// ---------------------------------------------------------------------------
extern "C" void kernel_launch(void* const* d_in, const int* in_sizes, int n_in,
                              void* d_out, int out_size, void* d_ws, size_t ws_size,
                              hipStream_t stream) {
    const float* Q  = (const float*)d_in[0];
    const float* K  = (const float*)d_in[1];
    const float* V  = (const float*)d_in[2];
    const float* Wq = (const float*)d_in[3];
    const float* bq = (const float*)d_in[4];
    const float* Wk = (const float*)d_in[5];
    const float* bk = (const float*)d_in[6];
    const float* Wv = (const float*)d_in[7];
    const float* bv = (const float*)d_in[8];
    const float* Wo = (const float*)d_in[9];
    const float* bo = (const float*)d_in[10];
    float* out = (float*)d_out;

    const size_t plane = (size_t)M_ROWS * D_SZ;   // 8.4M elems
    const size_t wsz   = (size_t)D_SZ * D_SZ;     // 1M elems
    const dim3 gg(M_ROWS / 128, D_SZ / 128), bb(256);
    const dim3 ag(S_SZ / 128, B_SZ * H_SZ);

    // Fast path: pre-convert Q/K/V and weights to bf16, then all-bf16 GEMMs
    // with counted-vmcnt pipelined global_load_lds staging.
    const size_t need_fast = (3 * plane + 4 * wsz) * sizeof(__bf16);
    if (ws_size >= need_fast) {
        __bf16* s0  = (__bf16*)d_ws;            // Qb / Kb / Vb (sequential reuse)
        __bf16* qw  = s0 + plane;               // q-proj out, later ctx (in-place)
        __bf16* kw  = s0 + 2 * plane;           // k-proj out
        __bf16* wgt = s0 + 3 * plane;           // Wqb,Wkb,Wvb,Wob
        __bf16* vw  = (__bf16*)d_out;           // v-proj out in d_out scratch
        const int p8 = (int)(plane / 8), w8 = (int)(wsz / 8);

        conv_bf16<<<512, bb, 0, stream>>>(Wq, wgt, w8);
        conv_bf16<<<512, bb, 0, stream>>>(Wk, wgt + wsz, w8);
        conv_bf16<<<512, bb, 0, stream>>>(Wv, wgt + 2 * wsz, w8);
        conv_bf16<<<512, bb, 0, stream>>>(Wo, wgt + 3 * wsz, w8);

        conv_bf16<<<2048, bb, 0, stream>>>(Q, s0, p8);
        gemm_nt_bias_g<__bf16><<<gg, bb, 0, stream>>>(
            s0, wgt, bq, qw, M_ROWS, D_SZ, D_SZ);
        conv_bf16<<<2048, bb, 0, stream>>>(K, s0, p8);
        gemm_nt_bias_g<__bf16><<<gg, bb, 0, stream>>>(
            s0, wgt + wsz, bk, kw, M_ROWS, D_SZ, D_SZ);
        conv_bf16<<<2048, bb, 0, stream>>>(V, s0, p8);
        gemm_nt_bias_g<__bf16><<<gg, bb, 0, stream>>>(
            s0, wgt + 2 * wsz, bv, vw, M_ROWS, D_SZ, D_SZ);

        attn_kernel<<<ag, bb, 0, stream>>>(qw, kw, vw, qw);

        gemm_nt_bias_g<float><<<gg, bb, 0, stream>>>(
            qw, wgt + 3 * wsz, bo, out, M_ROWS, D_SZ, D_SZ);
        return;
    }

    // Fallback (verified round-4 path): fp32 reg-staged GEMMs, 2 bf16 planes.
    if (ws_size < 2 * plane * sizeof(__bf16)) return;
    __bf16* qw = (__bf16*)d_ws;
    __bf16* kw = qw + plane;
    __bf16* vw = (__bf16*)d_out;
    __bf16* cw = qw;

    gemm_nt_bias<float, float, __bf16><<<gg, bb, 0, stream>>>(Q, Wq, bq, qw, M_ROWS, D_SZ, D_SZ);
    gemm_nt_bias<float, float, __bf16><<<gg, bb, 0, stream>>>(K, Wk, bk, kw, M_ROWS, D_SZ, D_SZ);
    gemm_nt_bias<float, float, __bf16><<<gg, bb, 0, stream>>>(V, Wv, bv, vw, M_ROWS, D_SZ, D_SZ);

    attn_kernel<<<ag, bb, 0, stream>>>(qw, kw, vw, cw);

    gemm_nt_bias<__bf16, float, float><<<gg, bb, 0, stream>>>(cw, Wo, bo, out,
                                                              M_ROWS, D_SZ, D_SZ);
}